// Round 8
// baseline (507.154 us; speedup 1.0000x reference)
//
#include <hip/hip_runtime.h>
#include <hip/hip_bf16.h>

#define UDIM    256
#define ODIM    128
#define ZDIM    1024
#define NSTEPS  48
#define BM      32
#define THREADS 1024
#define NBLOCKS 128   // 4096 / BM

// ws layout in ushort elements — FP16 bits:
//   KR: [0,       393216)   64 tiles x 12 kc x 64 lanes x 8
//   D : [393216,  425984)   8 tiles x 8 kc x 64 lanes x 8
#define KR_FRAGS 393216
#define D_FRAGS  32768

// sA cols: [0,128)=x, [128,384)=h buf0, [384,640)=h buf1, pad to 648.
// Stride 648 ushort = 324 dwords == 4 (mod 32): the 64-lane ds_read_b128
// window (banks 4*(cl+rg)+0..3) covers all 32 banks exactly 8x — uniform.
// Row bytes 1296 % 16 == 0 -> b128 aligned.
#define SA_W 648

typedef _Float16 f16x8 __attribute__((ext_vector_type(8)));
typedef float    f32x4 __attribute__((ext_vector_type(4)));

__device__ __forceinline__ ushort f2h_bits(float v) {
    _Float16 h = (_Float16)v;          // v_cvt_f16_f32, RNE
    return *reinterpret_cast<ushort*>(&h);
}
__device__ __forceinline__ float sigmoid_f(float x) {
    return 1.0f / (1.0f + __expf(-x));
}
__device__ __forceinline__ float tanh_f(float x) {
    return 1.0f - 2.0f / (__expf(2.0f * x) + 1.0f);
}

// ---- prep: pack weights into MFMA B-fragment order, fp16 (round-nearest) ----
__global__ void prep_weights(const float* __restrict__ kernel_w,   // [128,1024]
                             const float* __restrict__ rec_w,      // [256,1024]
                             const float* __restrict__ dense_w,    // [256,128]
                             ushort* __restrict__ ws) {
    int idx = blockIdx.x * blockDim.x + threadIdx.x;
    if (idx < KR_FRAGS) {
        int j  = idx & 7;
        int l  = (idx >> 3) & 63;
        int fc = idx >> 9;          // n*12 + kc
        int kc = fc % 12;
        int n  = fc / 12;
        int k   = kc * 32 + (l >> 4) * 8 + j;
        int col = n * 16 + (l & 15);
        float wv = (k < 128) ? kernel_w[k * ZDIM + col]
                             : rec_w[(k - 128) * ZDIM + col];
        ws[idx] = f2h_bits(wv);
    } else if (idx < KR_FRAGS + D_FRAGS) {
        int e  = idx - KR_FRAGS;
        int j  = e & 7;
        int l  = (e >> 3) & 63;
        int kc = (e >> 9) & 7;
        int n  = e >> 12;
        int k   = kc * 32 + (l >> 4) * 8 + j;
        int col = n * 16 + (l & 15);
        ws[KR_FRAGS + e] = f2h_bits(dense_w[k * ODIM + col]);
    }
}

// ---- main: BM=32, f16 single-pass, 2 barriers/step, no fusion ----
// Each B-fragment feeds 2 independent MFMAs (row-tiles rt=0,1): double the
// latency cover of BM=16 per load batch. 128 blocks halve per-XCD L2 demand
// (3.3 -> ~1.6 TB/s) — out of the queueing regime. Dense has exactly 16
// wave-tiles (8 n x 2 rt): all waves busy, no acc2 / fusion needed.
// r3's defects removed: no hi/lo dependent MFMA chains, dense from LDS.
// Load structure FROZEN per r4/r5: inline loads, runtime kc, unroll<=4.
__global__ __launch_bounds__(THREADS, 4) void lstm_mfma_kernel(
    const float* __restrict__ last_input,  // [4096,128]
    const float* __restrict__ h0,          // [4096,256]
    const float* __restrict__ c0,          // [4096,256]
    const float* __restrict__ bias,        // [1024]
    const float* __restrict__ dense_b,     // [128]
    const ushort* __restrict__ wsro,
    float* __restrict__ out)               // [4096,48,128]
{
    const ushort* KR = wsro;

    __shared__ ushort sA[BM][SA_W];                  // fp16 bits
    __shared__ __align__(16) ushort sDw[D_FRAGS];    // dense weights, fp16 bits

    const int t  = threadIdx.x;
    const int w  = t >> 6;          // wave 0..15
    const int l  = t & 63;
    const int cl = l & 15;          // A row within tile / C col
    const int rg = l >> 4;          // C rows 4*rg..+4, k-group
    const int blockRow = blockIdx.x * BM;

    // ---- stage dense weights into LDS (once) ----
    for (int i = t * 8; i < D_FRAGS; i += THREADS * 8)
        *reinterpret_cast<f16x8*>(&sDw[i]) =
            *reinterpret_cast<const f16x8*>(&wsro[KR_FRAGS + i]);

    // ---- stage x0 (cols 0..127) and h0 (buf1: cols 384..639) ----
    for (int i = t; i < BM * ODIM; i += THREADS) {
        int r = i >> 7, c = i & 127;
        sA[r][c] = f2h_bits(last_input[(blockRow + r) * ODIM + c]);
    }
    for (int i = t; i < BM * UDIM; i += THREADS) {
        int r = i >> 8, c = i & 255;
        sA[r][384 + c] = f2h_bits(h0[(blockRow + r) * UDIM + c]);
    }

    // ---- per-lane state: units u = 16*w + cl, rows rt*16 + 4*rg + r ----
    const int unit = 16 * w + cl;
    float cstate[2][4];
    #pragma unroll
    for (int rt = 0; rt < 2; ++rt)
        #pragma unroll
        for (int r = 0; r < 4; ++r)
            cstate[rt][r] = c0[(blockRow + rt * 16 + 4 * rg + r) * UDIM + unit];

    float bz[4];
    #pragma unroll
    for (int g = 0; g < 4; ++g)
        bz[g] = bias[256 * g + unit];

    const int dn  = w & 7;          // dense n-tile
    const int drt = w >> 3;         // dense row-tile
    const float db = dense_b[16 * dn + cl];

    __syncthreads();

    for (int s = 0; s < NSTEPS; ++s) {
        const int hrd = 128 + 256 * ((s + 1) & 1);  // h read base (prev step's buf)
        const int hb  = 128 + 256 * (s & 1);        // h write base (this step)

        // ======== GEMM1: Z[32,1024] = A[32,384] @ KR + bias (f16, 1 pass) ========
        f32x4 acc[4][2];
        #pragma unroll
        for (int g = 0; g < 4; ++g) {
            acc[g][0] = (f32x4){bz[g], bz[g], bz[g], bz[g]};
            acc[g][1] = (f32x4){bz[g], bz[g], bz[g], bz[g]};
        }

        #pragma unroll 4
        for (int kc = 0; kc < 12; ++kc) {
            const int koff = (kc < 4) ? (kc * 32 + rg * 8)
                                      : (hrd + (kc - 4) * 32 + rg * 8);
            f16x8 a0 = *reinterpret_cast<const f16x8*>(&sA[cl][koff]);
            f16x8 a1 = *reinterpret_cast<const f16x8*>(&sA[16 + cl][koff]);
            #pragma unroll
            for (int g = 0; g < 4; ++g) {
                const int n = w + 16 * g;
                const int fo = ((n * 12 + kc) * 64 + l) * 8;
                f16x8 b = *reinterpret_cast<const f16x8*>(KR + fo);
                acc[g][0] = __builtin_amdgcn_mfma_f32_16x16x32_f16(a0, b, acc[g][0], 0, 0, 0);
                acc[g][1] = __builtin_amdgcn_mfma_f32_16x16x32_f16(a1, b, acc[g][1], 0, 0, 0);
            }
        }

        // ======== gates + state update; h_new into the OTHER buffer ========
        // No barrier needed: buffer hb's previous readers (GEMM1(s-1)) finished
        // before B2(s-1) — two barriers ago.
        #pragma unroll
        for (int rt = 0; rt < 2; ++rt) {
            #pragma unroll
            for (int r = 0; r < 4; ++r) {
                float iv = sigmoid_f(acc[0][rt][r]);
                float fv = sigmoid_f(acc[1][rt][r]);
                float gv = tanh_f(acc[2][rt][r]);
                float ov = sigmoid_f(acc[3][rt][r]);
                float cn = fv * cstate[rt][r] + iv * gv;
                cstate[rt][r] = cn;
                float hv = ov * tanh_f(cn);
                sA[rt * 16 + 4 * rg + r][hb + unit] = f2h_bits(hv);
            }
        }
        __syncthreads();   // B2: h_new visible; orders GEMM1 x-reads vs dense y-writes

        // ======== dense: Y[32,128] = H[32,256] @ Wd + bd, relu — ALL 16 waves ========
        {
            f32x4 dacc = (f32x4){db, db, db, db};
            #pragma unroll
            for (int kc = 0; kc < 8; ++kc) {
                const int koff = hb + kc * 32 + rg * 8;
                f16x8 ah = *reinterpret_cast<const f16x8*>(&sA[drt * 16 + cl][koff]);
                f16x8 b  = *reinterpret_cast<const f16x8*>(&sDw[dn * 4096 + kc * 512 + l * 8]);
                dacc = __builtin_amdgcn_mfma_f32_16x16x32_f16(ah, b, dacc, 0, 0, 0);
            }
            #pragma unroll
            for (int r = 0; r < 4; ++r) {
                float y = fmaxf(dacc[r], 0.0f);
                int row = drt * 16 + 4 * rg + r;
                out[((size_t)(blockRow + row) * NSTEPS + s) * ODIM + 16 * dn + cl] = y;
                sA[row][16 * dn + cl] = f2h_bits(y);
            }
        }
        __syncthreads();   // B4: next-step x ready; hbuf reads done before rewrite
    }
}

extern "C" void kernel_launch(void* const* d_in, const int* in_sizes, int n_in,
                              void* d_out, int out_size, void* d_ws, size_t ws_size,
                              hipStream_t stream) {
    const float* last_input = (const float*)d_in[0];
    const float* h0         = (const float*)d_in[1];
    const float* c0         = (const float*)d_in[2];
    const float* kernel_w   = (const float*)d_in[3];
    const float* rec_w      = (const float*)d_in[4];
    const float* bias       = (const float*)d_in[5];
    const float* dense_w    = (const float*)d_in[6];
    const float* dense_b    = (const float*)d_in[7];
    float* out  = (float*)d_out;
    ushort* ws  = (ushort*)d_ws;

    const int prep_total = KR_FRAGS + D_FRAGS;
    hipLaunchKernelGGL(prep_weights, dim3((prep_total + 255) / 256), dim3(256), 0, stream,
                       kernel_w, rec_w, dense_w, ws);
    hipLaunchKernelGGL(lstm_mfma_kernel, dim3(NBLOCKS), dim3(THREADS), 0, stream,
                       last_input, h0, c0, bias, dense_b, (const ushort*)ws, out);
}